// Round 5
// baseline (1611.506 us; speedup 1.0000x reference)
//
#include <hip/hip_runtime.h>

// Problem constants (match reference)
constexpr int K    = 27;
constexpr int CIN  = 16;
constexpr int COUT = 4;
constexpr int NS   = 3;
constexpr int WSZ  = K * CIN * COUT;   // 1728 floats per stencil
constexpr int WPAD = WSZ + 8;          // bank-spread pad

// Chunked-gather configuration
constexpr int NCH  = 16;               // chunks of x (64K rows = 2MB bf16 each)
constexpr int CHSH = 16;               // chunk = nb >> 16
constexpr int NP   = 8;                // particles per compute thread
constexpr int TPB  = 256;
constexpr int NBLK = 512;              // 2 blocks/CU -> all co-resident
constexpr int T    = NBLK * TPB;       // 131072 threads
constexpr int EPT  = NP * K;           // 216 entries/thread
constexpr int ACCS = 34;               // LDS acc stride (words) per thread

typedef unsigned int uint;
typedef float  f32x4 __attribute__((ext_vector_type(4)));
typedef uint   u32x4 __attribute__((ext_vector_type(4)));

// ---- x fp32 -> bf16 (RNE), packed 2 per dword ----
__device__ __forceinline__ uint bf16_rne(float f) {
    uint u = __float_as_uint(f);
    u += 0x7FFFu + ((u >> 16) & 1u);
    return u >> 16;
}

__global__ __launch_bounds__(256) void cvt_kernel(
    const float* __restrict__ x, uint* __restrict__ xh, int nvec)
{
    int i = blockIdx.x * 256 + threadIdx.x;
    if (i >= nvec) return;                 // nvec = N*CIN/8
    const f32x4* xf = reinterpret_cast<const f32x4*>(x) + 2 * (size_t)i;
    f32x4 a = __builtin_nontemporal_load(&xf[0]);
    f32x4 b = __builtin_nontemporal_load(&xf[1]);
    u32x4 o;
    o.x = bf16_rne(a.x) | (bf16_rne(a.y) << 16);
    o.y = bf16_rne(a.z) | (bf16_rne(a.w) << 16);
    o.z = bf16_rne(b.x) | (bf16_rne(b.y) << 16);
    o.w = bf16_rne(b.z) | (bf16_rne(b.w) << 16);
    __builtin_nontemporal_store(o, &reinterpret_cast<u32x4*>(xh)[i]);
}

__device__ __forceinline__ float blo(uint u) { return __uint_as_float(u << 16); }
__device__ __forceinline__ float bhi(uint u) { return __uint_as_float(u & 0xFFFF0000u); }

// ---- pass 2: bucket each compute-thread's 216 taps by x-chunk ----
// Entry layout (wave-transposed, exact packing, no padding waste):
//   ent[w][pos][lane], pos = thread-local slot 0..215
// Entry bits: nb(20) << 10 | b(3) << 7 | s(2) << 5 | k(5)
__global__ __launch_bounds__(256) void bucket_kernel(
    const int* __restrict__ aprs,    // [n, 27]
    const int* __restrict__ lvl,     // [n]
    uint* __restrict__ ent,
    unsigned char* __restrict__ cnt, // [w][c][lane] u8
    int n)
{
    const int t    = blockIdx.x * TPB + threadIdx.x;
    const int w    = t >> 6;
    const int lane = t & 63;
    const int i0   = t * NP;

    int cc[NCH];
    #pragma unroll
    for (int c = 0; c < NCH; ++c) cc[c] = 0;

    // pass A: per-chunk histogram (static-indexed counters stay in regs)
    for (int b = 0; b < NP; ++b) {
        const int i = i0 + b;
        if (i >= n) break;
        const int* ap = aprs + (size_t)i * K;
        for (int j = 0; j < K; ++j) {
            const int ch = __builtin_nontemporal_load(&ap[j]) >> CHSH;
            #pragma unroll
            for (int c = 0; c < NCH; ++c) cc[c] += (ch == c) ? 1 : 0;
        }
    }

    // exclusive prefix -> write positions; store counts
    int pos[NCH];
    {
        int run = 0;
        #pragma unroll
        for (int c = 0; c < NCH; ++c) { pos[c] = run; run += cc[c]; }
    }
    #pragma unroll
    for (int c = 0; c < NCH; ++c)
        cnt[((size_t)w * NCH + c) * 64 + lane] = (unsigned char)cc[c];

    // pass B: re-stream aprs, emit packed entries at exact positions
    uint* eb = ent + (size_t)w * EPT * 64 + lane;
    for (int b = 0; b < NP; ++b) {
        const int i = i0 + b;
        if (i >= n) break;
        const uint s = (uint)lvl[i];
        const int* ap = aprs + (size_t)i * K;
        for (int j = 0; j < K; ++j) {
            const uint nb = (uint)__builtin_nontemporal_load(&ap[j]);
            const int  ch = (int)(nb >> CHSH);
            const uint e  = (nb << 10) | ((uint)b << 7) | (s << 5) | (uint)j;
            #pragma unroll
            for (int c = 0; c < NCH; ++c) {
                if (ch == c) { eb[(size_t)pos[c] * 64] = e; pos[c]++; }
            }
        }
    }
}

// ---- pass 3: persistent chunk-marched gather + contraction ----
__global__ __launch_bounds__(256) void compute_kernel(
    const uint* __restrict__ xh,     // [n, 8] dwords (16 bf16)
    const float* __restrict__ W,     // [3, 27, 16, 4]
    const uint* __restrict__ ent,
    const unsigned char* __restrict__ cnt,
    float* __restrict__ out,         // [n, 4]
    int n)
{
    __shared__ float Wl[NS * WPAD];
    __shared__ float accS[TPB * ACCS];

    for (int i = threadIdx.x; i < NS * WSZ; i += TPB) {
        int s = i / WSZ;
        Wl[s * WPAD + (i - s * WSZ)] = W[i];
    }
    float* __restrict__ myacc = &accS[threadIdx.x * ACCS];
    #pragma unroll
    for (int q = 0; q < NP * COUT; ++q) myacc[q] = 0.f;
    __syncthreads();

    const int t    = blockIdx.x * TPB + threadIdx.x;
    const int w    = t >> 6;
    const int lane = t & 63;
    const uint* __restrict__ eb = ent + (size_t)w * EPT * 64 + lane;
    const unsigned char* __restrict__ cb = cnt + (size_t)w * NCH * 64 + lane;

    int J = 0, end = 0;
    for (int c = 0; c < NCH; ++c) {
        end += (int)cb[(size_t)c * 64];
        bool v = (J < end);
        uint e = 0;
        if (v) e = eb[(size_t)J * 64];
        while (__any(v ? 1 : 0)) {
            // prefetch next entry (breaks e-load -> row-load serial chain)
            const bool vn = v && (J + 1 < end);
            uint en = 0;
            if (vn) en = eb[(size_t)(J + 1) * 64];
            if (v) {
                const uint nb = e >> 10;
                const uint b  = (e >> 7) & 7u;
                const uint s  = (e >> 5) & 3u;
                const uint k  = e & 31u;
                const u32x4* __restrict__ xr =
                    reinterpret_cast<const u32x4*>(xh + (size_t)nb * 8);
                const u32x4 p0 = xr[0];
                const u32x4 p1 = xr[1];
                const float* __restrict__ Wk = &Wl[s * WPAD + k * (CIN * COUT)];
                float xv[16];
                xv[ 0] = blo(p0.x); xv[ 1] = bhi(p0.x);
                xv[ 2] = blo(p0.y); xv[ 3] = bhi(p0.y);
                xv[ 4] = blo(p0.z); xv[ 5] = bhi(p0.z);
                xv[ 6] = blo(p0.w); xv[ 7] = bhi(p0.w);
                xv[ 8] = blo(p1.x); xv[ 9] = bhi(p1.x);
                xv[10] = blo(p1.y); xv[11] = bhi(p1.y);
                xv[12] = blo(p1.z); xv[13] = bhi(p1.z);
                xv[14] = blo(p1.w); xv[15] = bhi(p1.w);
                float a0 = 0.f, a1 = 0.f, a2 = 0.f, a3 = 0.f;
                #pragma unroll
                for (int cc2 = 0; cc2 < CIN; ++cc2) {
                    const float4 wv = *reinterpret_cast<const float4*>(&Wk[cc2 * COUT]);
                    a0 = fmaf(xv[cc2], wv.x, a0);
                    a1 = fmaf(xv[cc2], wv.y, a1);
                    a2 = fmaf(xv[cc2], wv.z, a2);
                    a3 = fmaf(xv[cc2], wv.w, a3);
                }
                float* __restrict__ ac = myacc + b * 4;
                ac[0] += a0; ac[1] += a1; ac[2] += a2; ac[3] += a3;
                ++J;
            }
            e = vn ? en : e;
            v = vn;
        }
    }

    // epilogue: relu + coalesced-ish per-thread contiguous writes
    #pragma unroll
    for (int b = 0; b < NP; ++b) {
        const int i = t * NP + b;
        if (i < n) {
            f32x4 o;
            o.x = fmaxf(myacc[b * 4 + 0], 0.f);
            o.y = fmaxf(myacc[b * 4 + 1], 0.f);
            o.z = fmaxf(myacc[b * 4 + 2], 0.f);
            o.w = fmaxf(myacc[b * 4 + 3], 0.f);
            __builtin_nontemporal_store(o, reinterpret_cast<f32x4*>(out) + i);
        }
    }
}

// ---- fallback: round-4 flat gather kernel ----
__global__ __launch_bounds__(256) void outblock_bf16(
    const uint*  __restrict__ xh,
    const float* __restrict__ W,
    const int*   __restrict__ aprs,
    const int*   __restrict__ lvl,
    float*       __restrict__ out,
    int n)
{
    __shared__ float Wl[NS * WPAD];
    for (int i = threadIdx.x; i < NS * WSZ; i += 256) {
        int s = i / WSZ;
        Wl[s * WPAD + (i - s * WSZ)] = W[i];
    }
    __syncthreads();

    int nIdx = blockIdx.x * 256 + threadIdx.x;
    if (nIdx >= n) return;

    const int s = __builtin_nontemporal_load(&lvl[nIdx]);
    const float* __restrict__ Ws = &Wl[s * WPAD];
    const int*   __restrict__ ap = aprs + (size_t)nIdx * K;

    float a0 = 0.f, a1 = 0.f, a2 = 0.f, a3 = 0.f;
    #pragma unroll 3
    for (int k = 0; k < K; ++k) {
        const int nb = __builtin_nontemporal_load(&ap[k]);
        const u32x4* __restrict__ xr =
            reinterpret_cast<const u32x4*>(xh + (size_t)nb * 8);
        const u32x4 p0 = xr[0];
        const u32x4 p1 = xr[1];
        const float* __restrict__ Wk = Ws + k * (CIN * COUT);
        float xv[16];
        xv[ 0] = blo(p0.x); xv[ 1] = bhi(p0.x);
        xv[ 2] = blo(p0.y); xv[ 3] = bhi(p0.y);
        xv[ 4] = blo(p0.z); xv[ 5] = bhi(p0.z);
        xv[ 6] = blo(p0.w); xv[ 7] = bhi(p0.w);
        xv[ 8] = blo(p1.x); xv[ 9] = bhi(p1.x);
        xv[10] = blo(p1.y); xv[11] = bhi(p1.y);
        xv[12] = blo(p1.z); xv[13] = bhi(p1.z);
        xv[14] = blo(p1.w); xv[15] = bhi(p1.w);
        #pragma unroll
        for (int c = 0; c < CIN; ++c) {
            const float4 wv = *reinterpret_cast<const float4*>(&Wk[c * COUT]);
            a0 = fmaf(xv[c], wv.x, a0);
            a1 = fmaf(xv[c], wv.y, a1);
            a2 = fmaf(xv[c], wv.z, a2);
            a3 = fmaf(xv[c], wv.w, a3);
        }
    }
    f32x4 o;
    o.x = fmaxf(a0, 0.f); o.y = fmaxf(a1, 0.f);
    o.z = fmaxf(a2, 0.f); o.w = fmaxf(a3, 0.f);
    __builtin_nontemporal_store(o, reinterpret_cast<f32x4*>(out) + nIdx);
}

// ---- last-resort fp32 fallback ----
__global__ __launch_bounds__(256) void outblock_f32(
    const float* __restrict__ x,
    const float* __restrict__ W,
    const int*   __restrict__ aprs,
    const int*   __restrict__ lvl,
    float*       __restrict__ out,
    int n)
{
    __shared__ float Wl[NS * WPAD];
    for (int i = threadIdx.x; i < NS * WSZ; i += 256) {
        int s = i / WSZ;
        Wl[s * WPAD + (i - s * WSZ)] = W[i];
    }
    __syncthreads();
    int nIdx = blockIdx.x * 256 + threadIdx.x;
    if (nIdx >= n) return;
    const int s = lvl[nIdx];
    const float* __restrict__ Ws = &Wl[s * WPAD];
    const int*   __restrict__ ap = aprs + (size_t)nIdx * K;
    float a0 = 0.f, a1 = 0.f, a2 = 0.f, a3 = 0.f;
    #pragma unroll 3
    for (int k = 0; k < K; ++k) {
        const int nb = ap[k];
        const float4* __restrict__ xr =
            reinterpret_cast<const float4*>(x + (size_t)nb * CIN);
        const float4 v0 = xr[0], v1 = xr[1], v2 = xr[2], v3 = xr[3];
        const float* __restrict__ Wk = Ws + k * (CIN * COUT);
        float xv[16];
        xv[ 0] = v0.x; xv[ 1] = v0.y; xv[ 2] = v0.z; xv[ 3] = v0.w;
        xv[ 4] = v1.x; xv[ 5] = v1.y; xv[ 6] = v1.z; xv[ 7] = v1.w;
        xv[ 8] = v2.x; xv[ 9] = v2.y; xv[10] = v2.z; xv[11] = v2.w;
        xv[12] = v3.x; xv[13] = v3.y; xv[14] = v3.z; xv[15] = v3.w;
        #pragma unroll
        for (int c = 0; c < CIN; ++c) {
            const float4 wv = *reinterpret_cast<const float4*>(&Wk[c * COUT]);
            a0 = fmaf(xv[c], wv.x, a0);
            a1 = fmaf(xv[c], wv.y, a1);
            a2 = fmaf(xv[c], wv.z, a2);
            a3 = fmaf(xv[c], wv.w, a3);
        }
    }
    float4 o;
    o.x = fmaxf(a0, 0.f); o.y = fmaxf(a1, 0.f);
    o.z = fmaxf(a2, 0.f); o.w = fmaxf(a3, 0.f);
    reinterpret_cast<float4*>(out)[nIdx] = o;
}

extern "C" void kernel_launch(void* const* d_in, const int* in_sizes, int n_in,
                              void* d_out, int out_size, void* d_ws, size_t ws_size,
                              hipStream_t stream) {
    const float* x    = (const float*)d_in[0];
    const float* W    = (const float*)d_in[1];
    const int*   aprs = (const int*)d_in[2];
    const int*   lvl  = (const int*)d_in[3];
    float*       out  = (float*)d_out;

    const int n = in_sizes[0] / CIN;               // N particles

    const size_t xhB  = (size_t)n * CIN * 2;                   // bf16 x copy
    const size_t entB = (size_t)(T / 64) * EPT * 64 * 4;       // entries
    const size_t cntB = (size_t)(T / 64) * NCH * 64;           // u8 counts
    const size_t needChunked = xhB + entB + cntB;

    if (ws_size >= needChunked && n <= T * NP) {
        uint* xh = (uint*)d_ws;
        uint* ent = (uint*)((char*)d_ws + xhB);
        unsigned char* cnt = (unsigned char*)((char*)d_ws + xhB + entB);
        const int nvec = n * CIN / 8;
        cvt_kernel<<<(nvec + 255) / 256, 256, 0, stream>>>(x, xh, nvec);
        bucket_kernel<<<NBLK, TPB, 0, stream>>>(aprs, lvl, ent, cnt, n);
        compute_kernel<<<NBLK, TPB, 0, stream>>>(xh, W, ent, cnt, out, n);
    } else if (ws_size >= xhB) {
        uint* xh = (uint*)d_ws;
        const int nvec = n * CIN / 8;
        cvt_kernel<<<(nvec + 255) / 256, 256, 0, stream>>>(x, xh, nvec);
        outblock_bf16<<<(n + 255) / 256, 256, 0, stream>>>(xh, W, aprs, lvl, out, n);
    } else {
        outblock_f32<<<(n + 255) / 256, 256, 0, stream>>>(x, W, aprs, lvl, out, n);
    }
}

// Round 6
// 922.061 us; speedup vs baseline: 1.7477x; 1.7477x over previous
//
#include <hip/hip_runtime.h>

// Problem constants (match reference)
constexpr int K    = 27;
constexpr int CIN  = 16;
constexpr int COUT = 4;
constexpr int NS   = 3;
constexpr int WSZ  = K * CIN * COUT;   // 1728 floats per stencil
constexpr int WPAD = WSZ + 8;          // pad for fallback kernel

// Chunked-gather configuration
constexpr int NCH  = 16;               // chunks of x (64K rows = 2MB bf16 each)
constexpr int CHSH = 16;               // chunk = nb >> 16 (requires n <= 2^20)
constexpr int NPW  = 512;              // particles per wave (8 per lane)
constexpr int EPW  = NPW * K;          // 13824 entries per wave
constexpr int NW   = 2048;             // waves total
constexpr int WREG = 68;               // padded W region stride (dwords): 68%32=4 -> 8 bank phases
constexpr int ASTR = 5;                // acc stride (words): 32 bank phases for atomics

typedef unsigned int uint;
typedef float  f32x4 __attribute__((ext_vector_type(4)));
typedef uint   u32x4 __attribute__((ext_vector_type(4)));

// ---- pass 1: x fp32 -> bf16 (RNE), packed 2 per dword ----
__device__ __forceinline__ uint bf16_rne(float f) {
    uint u = __float_as_uint(f);
    u += 0x7FFFu + ((u >> 16) & 1u);
    return u >> 16;
}

__global__ __launch_bounds__(256) void cvt_kernel(
    const float* __restrict__ x, uint* __restrict__ xh, int nvec)
{
    int i = blockIdx.x * 256 + threadIdx.x;
    if (i >= nvec) return;                 // nvec = N*CIN/8
    const f32x4* xf = reinterpret_cast<const f32x4*>(x) + 2 * (size_t)i;
    f32x4 a = __builtin_nontemporal_load(&xf[0]);
    f32x4 b = __builtin_nontemporal_load(&xf[1]);
    u32x4 o;
    o.x = bf16_rne(a.x) | (bf16_rne(a.y) << 16);
    o.y = bf16_rne(a.z) | (bf16_rne(a.w) << 16);
    o.z = bf16_rne(b.x) | (bf16_rne(b.y) << 16);
    o.w = bf16_rne(b.z) | (bf16_rne(b.w) << 16);
    __builtin_nontemporal_store(o, &reinterpret_cast<u32x4*>(xh)[i]);
}

__device__ __forceinline__ float blo(uint u) { return __uint_as_float(u << 16); }
__device__ __forceinline__ float bhi(uint u) { return __uint_as_float(u & 0xFFFF0000u); }

// ---- pass 2: per-wave counting sort of taps by x-chunk ----
// Entry: nbrel(16) << 16 | dest(9) << 7 | s(2) << 5 | j(5); dest = lane*8 + b.
// One wave per block. All loads PLAIN (L1/L2 retention for 2nd pass).
__global__ __launch_bounds__(64) void bucket_kernel(
    const int* __restrict__ aprs,    // [n, 27]
    const int* __restrict__ lvl,     // [n]
    uint* __restrict__ ent,          // [NW, EPW]
    int*  __restrict__ cnt,          // [NW, NCH]
    int n)
{
    __shared__ uint stage[EPW];          // 55.3 KB
    __shared__ int  posL[NCH * 64];      // per-(chunk,lane) cursors

    const int w    = blockIdx.x;
    const int lane = threadIdx.x;
    const int i0   = w * NPW + lane * 8;     // first particle of this lane
    const int* __restrict__ ap = aprs + (size_t)i0 * K;  // 216 contiguous ints

    // zero cursors (used as histogram)
    #pragma unroll
    for (int c = 0; c < NCH; ++c) posL[c * 64 + lane] = 0;
    __syncthreads();

    // pass A: histogram into LDS (lane-private cells, bank-conflict-free)
    for (int b = 0; b < 8; ++b) {
        if (i0 + b < n) {
            for (int j = 0; j < K; ++j) {
                const int ch = (int)(((uint)ap[b * K + j]) >> CHSH);
                posL[ch * 64 + lane] += 1;
            }
        }
    }
    __syncthreads();

    // wave scans: per chunk, exclusive-over-lanes prefix + running chunk bases
    int tot[NCH];
    int run = 0;
    #pragma unroll
    for (int c = 0; c < NCH; ++c) {
        const int cc = posL[c * 64 + lane];
        int v = cc;
        #pragma unroll
        for (int off = 1; off < 64; off <<= 1) {
            const int m = __shfl_up(v, off);
            if (lane >= off) v += m;
        }
        tot[c] = __shfl(v, 63);
        posL[c * 64 + lane] = run + (v - cc);   // this lane's first slot in chunk c
        run += tot[c];
    }
    __syncthreads();

    // pass B: emit packed entries at deterministic positions (aprs re-read hits L1/L2)
    for (int b = 0; b < 8; ++b) {
        if (i0 + b < n) {
            const uint s = (uint)lvl[i0 + b];
            const uint deststag = (uint)((lane << 3) | b) << 7 | (s << 5);
            for (int j = 0; j < K; ++j) {
                const uint nb = (uint)ap[b * K + j];
                const int  ch = (int)(nb >> CHSH);
                const int  p  = posL[ch * 64 + lane];
                posL[ch * 64 + lane] = p + 1;
                stage[p] = ((nb & 0xFFFFu) << 16) | deststag | (uint)j;
            }
        }
    }
    __syncthreads();

    // coalesced dump of valid entries
    uint* __restrict__ eb = ent + (size_t)w * EPW;
    for (int r = lane; r < run; r += 64) eb[r] = stage[r];

    if (lane == 0) {
        #pragma unroll
        for (int c = 0; c < NCH; ++c) cnt[w * NCH + c] = tot[c];
    }
}

// ---- pass 3: chunk-marched gather + contraction, LDS-atomic accumulation ----
__global__ __launch_bounds__(256) void compute_kernel(
    const uint*  __restrict__ xh,    // [n, 8] dwords (16 bf16)
    const float* __restrict__ Wg,    // [3, 27, 16, 4] f32
    const uint*  __restrict__ ent,
    const int*   __restrict__ cnt,
    float*       __restrict__ out,   // [n, 4]
    int n)
{
    __shared__ float Wl[NS * K * WREG];      // 81 regions * 68 dwords = 22 KB
    __shared__ float acc[4 * NPW * ASTR];    // 4 waves * 512 * 5 = 40 KB

    const int tid = threadIdx.x;
    // stage W with 68-word region stride (8 bank phases for random-region b128 reads)
    for (int idx = tid; idx < NS * K * 64; idx += 256) {
        const int region = idx >> 6, g = idx & 63;
        Wl[region * WREG + g] = Wg[idx];
    }
    for (int idx = tid; idx < 4 * NPW * ASTR; idx += 256) acc[idx] = 0.f;
    __syncthreads();

    const int widx = tid >> 6, lane = tid & 63;
    const int w = blockIdx.x * 4 + widx;
    float* __restrict__ myacc = acc + widx * NPW * ASTR;
    const uint* __restrict__ eb = ent + (size_t)w * EPW;

    int bs = 0;
    for (int c = 0; c < NCH; ++c) {
        const int m = cnt[w * NCH + c];       // wave-uniform
        for (int r0 = 0; r0 < m; r0 += 64) {
            const int idx = r0 + lane;
            if (idx < m) {
                const uint e    = eb[bs + idx];              // coalesced
                const uint nb   = ((uint)c << CHSH) | (e >> 16);
                const int  dest = (int)((e >> 7) & 511u);
                const int  sk   = (int)((e >> 5) & 3u) * K + (int)(e & 31u);
                const u32x4* __restrict__ xr =
                    reinterpret_cast<const u32x4*>(xh + (size_t)nb * 8);
                const u32x4 p0 = xr[0];                      // L2-resident chunk
                const u32x4 p1 = xr[1];
                uint xd[8];
                xd[0]=p0.x; xd[1]=p0.y; xd[2]=p0.z; xd[3]=p0.w;
                xd[4]=p1.x; xd[5]=p1.y; xd[6]=p1.z; xd[7]=p1.w;
                const float* __restrict__ wr = &Wl[sk * WREG];
                float a0=0.f, a1=0.f, a2=0.f, a3=0.f;
                #pragma unroll
                for (int cc2 = 0; cc2 < CIN; ++cc2) {
                    const f32x4 wv = *reinterpret_cast<const f32x4*>(wr + cc2 * 4);
                    const float xc = (cc2 & 1) ? bhi(xd[cc2 >> 1]) : blo(xd[cc2 >> 1]);
                    a0 = fmaf(xc, wv.x, a0);
                    a1 = fmaf(xc, wv.y, a1);
                    a2 = fmaf(xc, wv.z, a2);
                    a3 = fmaf(xc, wv.w, a3);
                }
                float* __restrict__ ac = myacc + dest * ASTR;
                atomicAdd(ac + 0, a0);
                atomicAdd(ac + 1, a1);
                atomicAdd(ac + 2, a2);
                atomicAdd(ac + 3, a3);
            }
        }
        bs += m;
    }
    __syncthreads();

    // epilogue: relu + coalesced f32x4 stores
    const int pbase = blockIdx.x * (4 * NPW);
    for (int j = tid; j < 4 * NPW; j += 256) {
        const int p = pbase + j;
        if (p < n) {
            const float* __restrict__ ac = acc + j * ASTR;
            f32x4 o;
            o.x = fmaxf(ac[0], 0.f);
            o.y = fmaxf(ac[1], 0.f);
            o.z = fmaxf(ac[2], 0.f);
            o.w = fmaxf(ac[3], 0.f);
            __builtin_nontemporal_store(o, reinterpret_cast<f32x4*>(out) + p);
        }
    }
}

// ---- fallback: round-4 flat gather kernel (proven 490 us) ----
__global__ __launch_bounds__(256) void outblock_bf16(
    const uint*  __restrict__ xh,
    const float* __restrict__ W,
    const int*   __restrict__ aprs,
    const int*   __restrict__ lvl,
    float*       __restrict__ out,
    int n)
{
    __shared__ float Wl[NS * WPAD];
    for (int i = threadIdx.x; i < NS * WSZ; i += 256) {
        int s = i / WSZ;
        Wl[s * WPAD + (i - s * WSZ)] = W[i];
    }
    __syncthreads();

    int nIdx = blockIdx.x * 256 + threadIdx.x;
    if (nIdx >= n) return;

    const int s = lvl[nIdx];
    const float* __restrict__ Ws = &Wl[s * WPAD];
    const int*   __restrict__ ap = aprs + (size_t)nIdx * K;

    float a0 = 0.f, a1 = 0.f, a2 = 0.f, a3 = 0.f;
    #pragma unroll 3
    for (int k = 0; k < K; ++k) {
        const int nb = ap[k];
        const u32x4* __restrict__ xr =
            reinterpret_cast<const u32x4*>(xh + (size_t)nb * 8);
        const u32x4 p0 = xr[0];
        const u32x4 p1 = xr[1];
        const float* __restrict__ Wk = Ws + k * (CIN * COUT);
        float xv[16];
        xv[ 0] = blo(p0.x); xv[ 1] = bhi(p0.x);
        xv[ 2] = blo(p0.y); xv[ 3] = bhi(p0.y);
        xv[ 4] = blo(p0.z); xv[ 5] = bhi(p0.z);
        xv[ 6] = blo(p0.w); xv[ 7] = bhi(p0.w);
        xv[ 8] = blo(p1.x); xv[ 9] = bhi(p1.x);
        xv[10] = blo(p1.y); xv[11] = bhi(p1.y);
        xv[12] = blo(p1.z); xv[13] = bhi(p1.z);
        xv[14] = blo(p1.w); xv[15] = bhi(p1.w);
        #pragma unroll
        for (int cq = 0; cq < CIN; ++cq) {
            const float4 wv = *reinterpret_cast<const float4*>(&Wk[cq * COUT]);
            a0 = fmaf(xv[cq], wv.x, a0);
            a1 = fmaf(xv[cq], wv.y, a1);
            a2 = fmaf(xv[cq], wv.z, a2);
            a3 = fmaf(xv[cq], wv.w, a3);
        }
    }
    f32x4 o;
    o.x = fmaxf(a0, 0.f); o.y = fmaxf(a1, 0.f);
    o.z = fmaxf(a2, 0.f); o.w = fmaxf(a3, 0.f);
    __builtin_nontemporal_store(o, reinterpret_cast<f32x4*>(out) + nIdx);
}

// ---- last-resort fp32 fallback ----
__global__ __launch_bounds__(256) void outblock_f32(
    const float* __restrict__ x,
    const float* __restrict__ W,
    const int*   __restrict__ aprs,
    const int*   __restrict__ lvl,
    float*       __restrict__ out,
    int n)
{
    __shared__ float Wl[NS * WPAD];
    for (int i = threadIdx.x; i < NS * WSZ; i += 256) {
        int s = i / WSZ;
        Wl[s * WPAD + (i - s * WSZ)] = W[i];
    }
    __syncthreads();
    int nIdx = blockIdx.x * 256 + threadIdx.x;
    if (nIdx >= n) return;
    const int s = lvl[nIdx];
    const float* __restrict__ Ws = &Wl[s * WPAD];
    const int*   __restrict__ ap = aprs + (size_t)nIdx * K;
    float a0 = 0.f, a1 = 0.f, a2 = 0.f, a3 = 0.f;
    #pragma unroll 3
    for (int k = 0; k < K; ++k) {
        const int nb = ap[k];
        const float4* __restrict__ xr =
            reinterpret_cast<const float4*>(x + (size_t)nb * CIN);
        const float4 v0 = xr[0], v1 = xr[1], v2 = xr[2], v3 = xr[3];
        const float* __restrict__ Wk = Ws + k * (CIN * COUT);
        float xv[16];
        xv[ 0] = v0.x; xv[ 1] = v0.y; xv[ 2] = v0.z; xv[ 3] = v0.w;
        xv[ 4] = v1.x; xv[ 5] = v1.y; xv[ 6] = v1.z; xv[ 7] = v1.w;
        xv[ 8] = v2.x; xv[ 9] = v2.y; xv[10] = v2.z; xv[11] = v2.w;
        xv[12] = v3.x; xv[13] = v3.y; xv[14] = v3.z; xv[15] = v3.w;
        #pragma unroll
        for (int cq = 0; cq < CIN; ++cq) {
            const float4 wv = *reinterpret_cast<const float4*>(&Wk[cq * COUT]);
            a0 = fmaf(xv[cq], wv.x, a0);
            a1 = fmaf(xv[cq], wv.y, a1);
            a2 = fmaf(xv[cq], wv.z, a2);
            a3 = fmaf(xv[cq], wv.w, a3);
        }
    }
    float4 o;
    o.x = fmaxf(a0, 0.f); o.y = fmaxf(a1, 0.f);
    o.z = fmaxf(a2, 0.f); o.w = fmaxf(a3, 0.f);
    reinterpret_cast<float4*>(out)[nIdx] = o;
}

extern "C" void kernel_launch(void* const* d_in, const int* in_sizes, int n_in,
                              void* d_out, int out_size, void* d_ws, size_t ws_size,
                              hipStream_t stream) {
    const float* x    = (const float*)d_in[0];
    const float* W    = (const float*)d_in[1];
    const int*   aprs = (const int*)d_in[2];
    const int*   lvl  = (const int*)d_in[3];
    float*       out  = (float*)d_out;

    const int n = in_sizes[0] / CIN;               // N particles

    const size_t xhB  = (size_t)n * CIN * 2;                 // bf16 x copy
    const size_t entB = (size_t)NW * EPW * 4;                // 113.2 MB entries
    const size_t cntB = (size_t)NW * NCH * 4;                // 131 KB counts
    const size_t needChunked = xhB + entB + cntB;

    if (ws_size >= needChunked && n <= (NW * NPW)) {
        uint* xh  = (uint*)d_ws;
        uint* ent = (uint*)((char*)d_ws + xhB);
        int*  cnt = (int*)((char*)d_ws + xhB + entB);
        const int nvec = n * CIN / 8;
        cvt_kernel<<<(nvec + 255) / 256, 256, 0, stream>>>(x, xh, nvec);
        bucket_kernel<<<NW, 64, 0, stream>>>(aprs, lvl, ent, cnt, n);
        compute_kernel<<<NW / 4, 256, 0, stream>>>(xh, W, ent, cnt, out, n);
    } else if (ws_size >= xhB) {
        uint* xh = (uint*)d_ws;
        const int nvec = n * CIN / 8;
        cvt_kernel<<<(nvec + 255) / 256, 256, 0, stream>>>(x, xh, nvec);
        outblock_bf16<<<(n + 255) / 256, 256, 0, stream>>>(xh, W, aprs, lvl, out, n);
    } else {
        outblock_f32<<<(n + 255) / 256, 256, 0, stream>>>(x, W, aprs, lvl, out, n);
    }
}

// Round 7
// 902.942 us; speedup vs baseline: 1.7847x; 1.0212x over previous
//
#include <hip/hip_runtime.h>

// Problem constants (match reference)
constexpr int K    = 27;
constexpr int CIN  = 16;
constexpr int COUT = 4;
constexpr int NS   = 3;
constexpr int WSZ  = K * CIN * COUT;   // 1728 floats per stencil
constexpr int WPAD = WSZ + 8;          // pad for fallback kernel

// Chunked-gather configuration
constexpr int NCH  = 16;               // chunks of x (64K rows = 2MB bf16 each)
constexpr int CHSH = 16;               // chunk = nb >> 16 (requires n <= 2^20)
constexpr int NPW  = 256;              // particles per wave (4 per lane)
constexpr int NPL  = 4;                // particles per lane
constexpr int EPW  = NPW * K;          // 6912 entries per wave
constexpr int NW   = 4096;             // waves total (NW*NPW = 1,048,576)
constexpr int MAXR = EPW / 64 + NCH;   // 124 max rounds per wave
constexpr int ASTR = 5;                // acc stride (words), coprime with 32
constexpr int WREG = 34;               // W region stride in dwords: 2*sk mod 32 -> 16 bank phases

typedef unsigned int uint;
typedef float  f32x4 __attribute__((ext_vector_type(4)));
typedef uint   u32x4 __attribute__((ext_vector_type(4)));
typedef uint   u32x2 __attribute__((ext_vector_type(2)));

// ---- helpers ----
__device__ __forceinline__ uint bf16_rne(float f) {
    uint u = __float_as_uint(f);
    u += 0x7FFFu + ((u >> 16) & 1u);
    return u >> 16;
}
__device__ __forceinline__ float blo(uint u) { return __uint_as_float(u << 16); }
__device__ __forceinline__ float bhi(uint u) { return __uint_as_float(u & 0xFFFF0000u); }

// ---- pass 1: x fp32 -> bf16 (RNE), packed 2 per dword ----
__global__ __launch_bounds__(256) void cvt_kernel(
    const float* __restrict__ x, uint* __restrict__ xh, int nvec)
{
    int i = blockIdx.x * 256 + threadIdx.x;
    if (i >= nvec) return;                 // nvec = N*CIN/8
    const f32x4* xf = reinterpret_cast<const f32x4*>(x) + 2 * (size_t)i;
    f32x4 a = __builtin_nontemporal_load(&xf[0]);
    f32x4 b = __builtin_nontemporal_load(&xf[1]);
    u32x4 o;
    o.x = bf16_rne(a.x) | (bf16_rne(a.y) << 16);
    o.y = bf16_rne(a.z) | (bf16_rne(a.w) << 16);
    o.z = bf16_rne(b.x) | (bf16_rne(b.y) << 16);
    o.w = bf16_rne(b.z) | (bf16_rne(b.w) << 16);
    __builtin_nontemporal_store(o, &reinterpret_cast<u32x4*>(xh)[i]);
}

// ---- pass 2: per-wave counting sort of taps by x-chunk ----
// Entry: nbrel(16)<<16 | dest(8)<<7 | s(2)<<5 | j(5); dest = lane*4 + b.
__global__ __launch_bounds__(64) void bucket_kernel(
    const int* __restrict__ aprs,    // [n, 27]
    const int* __restrict__ lvl,     // [n]
    uint* __restrict__ ent,          // [NW, EPW]
    int*  __restrict__ cnt,          // [NW, NCH]
    int n)
{
    __shared__ uint stage[EPW];          // 27.6 KB
    __shared__ int  posL[NCH * 64];      // 4 KB

    const int w    = blockIdx.x;
    const int lane = threadIdx.x;
    const int i0   = w * NPW + lane * NPL;
    const int* __restrict__ ap = aprs + (size_t)i0 * K;  // 108 contiguous ints

    #pragma unroll
    for (int c = 0; c < NCH; ++c) posL[c * 64 + lane] = 0;
    __syncthreads();

    // pass A: histogram (lane-private cells: bank = lane mod 32, conflict-free)
    for (int b = 0; b < NPL; ++b) {
        if (i0 + b < n) {
            for (int j = 0; j < K; ++j) {
                const int ch = (int)(((uint)ap[b * K + j]) >> CHSH);
                posL[ch * 64 + lane] += 1;
            }
        }
    }
    __syncthreads();

    // per-chunk exclusive-over-lanes scans + running chunk bases
    int tot[NCH];
    int run = 0;
    #pragma unroll
    for (int c = 0; c < NCH; ++c) {
        const int cc = posL[c * 64 + lane];
        int v = cc;
        #pragma unroll
        for (int off = 1; off < 64; off <<= 1) {
            const int m = __shfl_up(v, off);
            if (lane >= off) v += m;
        }
        tot[c] = __shfl(v, 63);
        posL[c * 64 + lane] = run + (v - cc);
        run += tot[c];
    }
    __syncthreads();

    // pass B: emit packed entries (aprs re-read hits L1/L2)
    for (int b = 0; b < NPL; ++b) {
        if (i0 + b < n) {
            const uint s = (uint)lvl[i0 + b];
            const uint deststag = ((uint)((lane << 2) | b) << 7) | (s << 5);
            for (int j = 0; j < K; ++j) {
                const uint nb = (uint)ap[b * K + j];
                const int  ch = (int)(nb >> CHSH);
                const int  p  = posL[ch * 64 + lane];
                posL[ch * 64 + lane] = p + 1;
                stage[p] = ((nb & 0xFFFFu) << 16) | deststag | (uint)j;
            }
        }
    }
    __syncthreads();

    uint* __restrict__ eb = ent + (size_t)w * EPW;
    for (int r = lane; r < run; r += 64) eb[r] = stage[r];

    if (lane == 0) {
        #pragma unroll
        for (int c = 0; c < NCH; ++c) cnt[w * NCH + c] = tot[c];
    }
}

// ---- pass 3: chunk-marched gather, flat round loop, 3-deep pipeline ----
__global__ __launch_bounds__(256, 4) void compute_kernel(
    const uint*  __restrict__ xh,    // [n, 8] dwords (16 bf16)
    const float* __restrict__ Wg,    // [3, 27, 16, 4] f32
    const uint*  __restrict__ ent,
    const int*   __restrict__ cnt,
    float*       __restrict__ out,   // [n, 4]
    int n)
{
    __shared__ __align__(16) uint Wb[NS * K * WREG];   // 81*34 dwords = 11 KB (bf16 pairs)
    __shared__ float accS[4 * NPW * ASTR];             // 20.5 KB
    __shared__ uint tblB[4 * MAXR];                    // ebase | (chunk<<16)
    __shared__ uint tblL[4 * MAXR];                    // elim
    __shared__ int  Rsh[4];

    const int tid = threadIdx.x;

    // stage W as bf16 pairs, region stride 34 dwords (16 bank phases on b64 reads)
    for (int idx = tid; idx < NS * K * 32; idx += 256) {
        const int region = idx >> 5, g = idx & 31;
        const float f0 = Wg[region * 64 + g * 2 + 0];
        const float f1 = Wg[region * 64 + g * 2 + 1];
        Wb[region * WREG + g] = bf16_rne(f0) | (bf16_rne(f1) << 16);
    }
    for (int idx = tid; idx < 4 * NPW * ASTR; idx += 256) accS[idx] = 0.f;
    __syncthreads();

    const int widx = tid >> 6, lane = tid & 63;
    const int w = blockIdx.x * 4 + widx;

    // build per-wave round table: lanes 0..15 own one chunk each
    {
        int m_c = 0, rnds = 0;
        if (lane < NCH) {
            m_c  = cnt[w * NCH + lane];
            rnds = (m_c + 63) >> 6;
        }
        int mscan = m_c, rscan = rnds;
        #pragma unroll
        for (int off = 1; off < NCH; off <<= 1) {
            const int tm = __shfl_up(mscan, off);
            const int tr = __shfl_up(rscan, off);
            if (lane >= off) { mscan += tm; rscan += tr; }
        }
        const int bs = mscan - m_c;     // exclusive prefix of entries
        const int r0 = rscan - rnds;    // exclusive prefix of rounds
        const int Rtot = __shfl(rscan, NCH - 1);
        if (lane < NCH) {
            for (int i = 0; i < rnds; ++i) {
                tblB[widx * MAXR + r0 + i] = (uint)(bs + i * 64) | ((uint)lane << 16);
                tblL[widx * MAXR + r0 + i] = (uint)(bs + m_c);
            }
        }
        if (lane == 0) Rsh[widx] = Rtot;
    }
    __syncthreads();

    const int R = Rsh[widx];
    const uint* __restrict__ eb  = ent + (size_t)w * EPW;
    const uint* __restrict__ tB  = &tblB[widx * MAXR];
    const uint* __restrict__ tL  = &tblL[widx * MAXR];
    float* __restrict__ myacc    = accS + widx * NPW * ASTR;

    if (R > 0) {
        // prologue: rounds 0 and 1
        uint b0 = tB[0], l0 = tL[0];
        const int rc1 = (1 < R) ? 1 : 0;
        uint b1 = tB[rc1], l1 = tL[rc1];

        int i0c = min((int)(b0 & 0xFFFFu) + lane, (int)l0 - 1);
        uint eC = eb[i0c];
        int i1c = min((int)(b1 & 0xFFFFu) + lane, (int)l1 - 1);
        uint eN = eb[i1c];

        const uint nb0 = ((b0 >> 16) << CHSH) | (eC >> 16);
        const u32x4* __restrict__ xr0 =
            reinterpret_cast<const u32x4*>(xh + (size_t)nb0 * 8);
        u32x4 xC0 = xr0[0];
        u32x4 xC1 = xr0[1];

        for (int r = 0; r < R; ++r) {
            // (1) issue entry prefetch for round r+2
            const int rc2 = (r + 2 < R) ? r + 2 : R - 1;
            const uint b2 = tB[rc2], l2 = tL[rc2];
            const int  i2c = min((int)(b2 & 0xFFFFu) + lane, (int)l2 - 1);
            const uint eF = eb[i2c];

            // (2) issue x loads for round r+1 (eN arrived ~2 rounds ago)
            const uint nbN = ((b1 >> 16) << CHSH) | (eN >> 16);
            const u32x4* __restrict__ xrN =
                reinterpret_cast<const u32x4*>(xh + (size_t)nbN * 8);
            const u32x4 xN0 = xrN[0];
            const u32x4 xN1 = xrN[1];

            // (3) compute round r
            const bool valid = ((int)(b0 & 0xFFFFu) + lane) < (int)l0;
            const uint dest = (eC >> 7) & 0xFFu;
            const uint sk   = ((eC >> 5) & 3u) * K + (eC & 31u);
            const uint* __restrict__ wr = &Wb[sk * WREG];

            uint xd[8];
            xd[0] = xC0.x; xd[1] = xC0.y; xd[2] = xC0.z; xd[3] = xC0.w;
            xd[4] = xC1.x; xd[5] = xC1.y; xd[6] = xC1.z; xd[7] = xC1.w;

            float a0 = 0.f, a1 = 0.f, a2 = 0.f, a3 = 0.f;
            #pragma unroll
            for (int cc = 0; cc < CIN; ++cc) {
                const u32x2 wv = *reinterpret_cast<const u32x2*>(wr + cc * 2); // ds_read_b64
                const float xc = (cc & 1) ? bhi(xd[cc >> 1]) : blo(xd[cc >> 1]);
                a0 = fmaf(xc, blo(wv.x), a0);
                a1 = fmaf(xc, bhi(wv.x), a1);
                a2 = fmaf(xc, blo(wv.y), a2);
                a3 = fmaf(xc, bhi(wv.y), a3);
            }
            if (valid) {
                float* __restrict__ ac = myacc + dest * ASTR;
                atomicAdd(ac + 0, a0);
                atomicAdd(ac + 1, a1);
                atomicAdd(ac + 2, a2);
                atomicAdd(ac + 3, a3);
            }

            // rotate pipeline
            b0 = b1; l0 = l1; eC = eN; xC0 = xN0; xC1 = xN1;
            b1 = b2; l1 = l2; eN = eF;
        }
    }
    __syncthreads();

    // epilogue: relu + coalesced stores for this block's 1024 particles
    const int pbase = blockIdx.x * (4 * NPW);
    for (int j = tid; j < 4 * NPW; j += 256) {
        const int p = pbase + j;
        if (p < n) {
            const float* __restrict__ ac = accS + j * ASTR;
            f32x4 o;
            o.x = fmaxf(ac[0], 0.f);
            o.y = fmaxf(ac[1], 0.f);
            o.z = fmaxf(ac[2], 0.f);
            o.w = fmaxf(ac[3], 0.f);
            __builtin_nontemporal_store(o, reinterpret_cast<f32x4*>(out) + p);
        }
    }
}

// ---- fallback: round-4 flat gather kernel (proven ~474 us) ----
__global__ __launch_bounds__(256) void outblock_bf16(
    const uint*  __restrict__ xh,
    const float* __restrict__ W,
    const int*   __restrict__ aprs,
    const int*   __restrict__ lvl,
    float*       __restrict__ out,
    int n)
{
    __shared__ float Wl[NS * WPAD];
    for (int i = threadIdx.x; i < NS * WSZ; i += 256) {
        int s = i / WSZ;
        Wl[s * WPAD + (i - s * WSZ)] = W[i];
    }
    __syncthreads();

    int nIdx = blockIdx.x * 256 + threadIdx.x;
    if (nIdx >= n) return;

    const int s = lvl[nIdx];
    const float* __restrict__ Ws = &Wl[s * WPAD];
    const int*   __restrict__ ap = aprs + (size_t)nIdx * K;

    float a0 = 0.f, a1 = 0.f, a2 = 0.f, a3 = 0.f;
    #pragma unroll 3
    for (int k = 0; k < K; ++k) {
        const int nb = ap[k];
        const u32x4* __restrict__ xr =
            reinterpret_cast<const u32x4*>(xh + (size_t)nb * 8);
        const u32x4 p0 = xr[0];
        const u32x4 p1 = xr[1];
        const float* __restrict__ Wk = Ws + k * (CIN * COUT);
        float xv[16];
        xv[ 0] = blo(p0.x); xv[ 1] = bhi(p0.x);
        xv[ 2] = blo(p0.y); xv[ 3] = bhi(p0.y);
        xv[ 4] = blo(p0.z); xv[ 5] = bhi(p0.z);
        xv[ 6] = blo(p0.w); xv[ 7] = bhi(p0.w);
        xv[ 8] = blo(p1.x); xv[ 9] = bhi(p1.x);
        xv[10] = blo(p1.y); xv[11] = bhi(p1.y);
        xv[12] = blo(p1.z); xv[13] = bhi(p1.z);
        xv[14] = blo(p1.w); xv[15] = bhi(p1.w);
        #pragma unroll
        for (int cq = 0; cq < CIN; ++cq) {
            const float4 wv = *reinterpret_cast<const float4*>(&Wk[cq * COUT]);
            a0 = fmaf(xv[cq], wv.x, a0);
            a1 = fmaf(xv[cq], wv.y, a1);
            a2 = fmaf(xv[cq], wv.z, a2);
            a3 = fmaf(xv[cq], wv.w, a3);
        }
    }
    f32x4 o;
    o.x = fmaxf(a0, 0.f); o.y = fmaxf(a1, 0.f);
    o.z = fmaxf(a2, 0.f); o.w = fmaxf(a3, 0.f);
    __builtin_nontemporal_store(o, reinterpret_cast<f32x4*>(out) + nIdx);
}

// ---- last-resort fp32 fallback ----
__global__ __launch_bounds__(256) void outblock_f32(
    const float* __restrict__ x,
    const float* __restrict__ W,
    const int*   __restrict__ aprs,
    const int*   __restrict__ lvl,
    float*       __restrict__ out,
    int n)
{
    __shared__ float Wl[NS * WPAD];
    for (int i = threadIdx.x; i < NS * WSZ; i += 256) {
        int s = i / WSZ;
        Wl[s * WPAD + (i - s * WSZ)] = W[i];
    }
    __syncthreads();
    int nIdx = blockIdx.x * 256 + threadIdx.x;
    if (nIdx >= n) return;
    const int s = lvl[nIdx];
    const float* __restrict__ Ws = &Wl[s * WPAD];
    const int*   __restrict__ ap = aprs + (size_t)nIdx * K;
    float a0 = 0.f, a1 = 0.f, a2 = 0.f, a3 = 0.f;
    #pragma unroll 3
    for (int k = 0; k < K; ++k) {
        const int nb = ap[k];
        const float4* __restrict__ xr =
            reinterpret_cast<const float4*>(x + (size_t)nb * CIN);
        const float4 v0 = xr[0], v1 = xr[1], v2 = xr[2], v3 = xr[3];
        const float* __restrict__ Wk = Ws + k * (CIN * COUT);
        float xv[16];
        xv[ 0] = v0.x; xv[ 1] = v0.y; xv[ 2] = v0.z; xv[ 3] = v0.w;
        xv[ 4] = v1.x; xv[ 5] = v1.y; xv[ 6] = v1.z; xv[ 7] = v1.w;
        xv[ 8] = v2.x; xv[ 9] = v2.y; xv[10] = v2.z; xv[11] = v2.w;
        xv[12] = v3.x; xv[13] = v3.y; xv[14] = v3.z; xv[15] = v3.w;
        #pragma unroll
        for (int cq = 0; cq < CIN; ++cq) {
            const float4 wv = *reinterpret_cast<const float4*>(&Wk[cq * COUT]);
            a0 = fmaf(xv[cq], wv.x, a0);
            a1 = fmaf(xv[cq], wv.y, a1);
            a2 = fmaf(xv[cq], wv.z, a2);
            a3 = fmaf(xv[cq], wv.w, a3);
        }
    }
    float4 o;
    o.x = fmaxf(a0, 0.f); o.y = fmaxf(a1, 0.f);
    o.z = fmaxf(a2, 0.f); o.w = fmaxf(a3, 0.f);
    reinterpret_cast<float4*>(out)[nIdx] = o;
}

extern "C" void kernel_launch(void* const* d_in, const int* in_sizes, int n_in,
                              void* d_out, int out_size, void* d_ws, size_t ws_size,
                              hipStream_t stream) {
    const float* x    = (const float*)d_in[0];
    const float* W    = (const float*)d_in[1];
    const int*   aprs = (const int*)d_in[2];
    const int*   lvl  = (const int*)d_in[3];
    float*       out  = (float*)d_out;

    const int n = in_sizes[0] / CIN;               // N particles

    const size_t xhB  = (size_t)n * CIN * 2;                 // 32 MB bf16 x copy
    const size_t entB = (size_t)NW * EPW * 4;                // 113.2 MB entries
    const size_t cntB = (size_t)NW * NCH * 4;                // 256 KB counts
    const size_t needChunked = xhB + entB + cntB;

    if (ws_size >= needChunked && n <= NW * NPW && n <= (1 << 20)) {
        uint* xh  = (uint*)d_ws;
        uint* ent = (uint*)((char*)d_ws + xhB);
        int*  cnt = (int*)((char*)d_ws + xhB + entB);
        const int nvec = n * CIN / 8;
        cvt_kernel<<<(nvec + 255) / 256, 256, 0, stream>>>(x, xh, nvec);
        bucket_kernel<<<NW, 64, 0, stream>>>(aprs, lvl, ent, cnt, n);
        compute_kernel<<<NW / 4, 256, 0, stream>>>(xh, W, ent, cnt, out, n);
    } else if (ws_size >= xhB) {
        uint* xh = (uint*)d_ws;
        const int nvec = n * CIN / 8;
        cvt_kernel<<<(nvec + 255) / 256, 256, 0, stream>>>(x, xh, nvec);
        outblock_bf16<<<(n + 255) / 256, 256, 0, stream>>>(xh, W, aprs, lvl, out, n);
    } else {
        outblock_f32<<<(n + 255) / 256, 256, 0, stream>>>(x, W, aprs, lvl, out, n);
    }
}

// Round 8
// 364.557 us; speedup vs baseline: 4.4205x; 2.4768x over previous
//
#include <hip/hip_runtime.h>

// Problem constants (match reference)
constexpr int K    = 27;
constexpr int CIN  = 16;
constexpr int COUT = 4;
constexpr int NS   = 3;
constexpr int WSZ  = K * CIN * COUT;   // 1728 floats per stencil
constexpr int WPAD = WSZ + 8;          // pad for fallback kernel

// Lane-owned chunk-sorted gather configuration
constexpr int NCH  = 16;               // sort key: chunk = nb >> 16 (2MB bf16 windows)
constexpr int CHSH = 16;
constexpr int NPL  = 4;                // particles per lane
constexpr int NPW  = 256;              // particles per wave (64 lanes * 4)
constexpr int RNDS = K * NPL;          // 108 fixed rounds per wave
constexpr int EPW  = RNDS * 64;        // 6912 entries per wave (column layout)
constexpr unsigned int SENT = 0xFFFFFFFFu;
constexpr int WREG = 34;               // W region stride (dwords), bf16 pairs

typedef unsigned int uint;
typedef float  f32x4 __attribute__((ext_vector_type(4)));
typedef uint   u32x4 __attribute__((ext_vector_type(4)));
typedef uint   u32x2 __attribute__((ext_vector_type(2)));

__device__ __forceinline__ uint bf16_rne(float f) {
    uint u = __float_as_uint(f);
    u += 0x7FFFu + ((u >> 16) & 1u);
    return u >> 16;
}
__device__ __forceinline__ float blo(uint u) { return __uint_as_float(u << 16); }
__device__ __forceinline__ float bhi(uint u) { return __uint_as_float(u & 0xFFFF0000u); }

// ---- pass 1: x fp32 -> bf16 (RNE), packed 2 per dword ----
__global__ __launch_bounds__(256) void cvt_kernel(
    const float* __restrict__ x, uint* __restrict__ xh, int nvec)
{
    int i = blockIdx.x * 256 + threadIdx.x;
    if (i >= nvec) return;                 // nvec = N*CIN/8
    const f32x4* xf = reinterpret_cast<const f32x4*>(x) + 2 * (size_t)i;
    f32x4 a = __builtin_nontemporal_load(&xf[0]);
    f32x4 b = __builtin_nontemporal_load(&xf[1]);
    u32x4 o;
    o.x = bf16_rne(a.x) | (bf16_rne(a.y) << 16);
    o.y = bf16_rne(a.z) | (bf16_rne(a.w) << 16);
    o.z = bf16_rne(b.x) | (bf16_rne(b.y) << 16);
    o.w = bf16_rne(b.z) | (bf16_rne(b.w) << 16);
    __builtin_nontemporal_store(o, &reinterpret_cast<u32x4*>(xh)[i]);
}

// ---- pass 2: per-LANE counting sort of own 108 taps by x-chunk ----
// Entry: nb(20)<<9 | b(2)<<7 | s(2)<<5 | j(5). Column layout ent[slot*64+lane].
// All LDS cells are lane-column-private (bank = lane mod 32, 2-way free).
__global__ __launch_bounds__(64) void bucket_kernel(
    const int* __restrict__ aprs,    // [n, 27]
    const int* __restrict__ lvl,     // [n]
    uint* __restrict__ ent,          // [NWAVES, EPW]
    int n)
{
    __shared__ uint stage[EPW];          // 27.6 KB
    __shared__ int  posL[NCH * 64];      // 4 KB cursors

    const int w    = blockIdx.x;
    const int lane = threadIdx.x;
    const int i0   = w * NPW + lane * NPL;
    const int* __restrict__ ap = aprs + (size_t)i0 * K;

    #pragma unroll
    for (int c = 0; c < NCH; ++c) posL[c * 64 + lane] = 0;
    for (int t = 0; t < RNDS; ++t) stage[t * 64 + lane] = SENT;

    // histogram of this lane's taps
    for (int b = 0; b < NPL; ++b) {
        if (i0 + b < n) {
            for (int j = 0; j < K; ++j) {
                const int ch = (int)(((uint)ap[b * K + j]) >> CHSH);
                posL[ch * 64 + lane] += 1;
            }
        }
    }
    // per-lane exclusive prefix (serial over 16 cells)
    int run = 0;
    #pragma unroll
    for (int c = 0; c < NCH; ++c) {
        const int cc = posL[c * 64 + lane];
        posL[c * 64 + lane] = run;
        run += cc;
    }
    // emit chunk-sorted entries into own column (aprs re-read hits L1)
    for (int b = 0; b < NPL; ++b) {
        if (i0 + b < n) {
            const uint s = (uint)lvl[i0 + b];
            const uint tag = ((uint)b << 7) | (s << 5);
            for (int j = 0; j < K; ++j) {
                const uint nb = (uint)ap[b * K + j];
                const int ch  = (int)(nb >> CHSH);
                const int slot = posL[ch * 64 + lane];
                posL[ch * 64 + lane] = slot + 1;
                stage[slot * 64 + lane] = (nb << 9) | tag | (uint)j;
            }
        }
    }
    // dump own column (coalesced across lanes)
    uint* __restrict__ eb = ent + (size_t)w * EPW;
    for (int t = 0; t < RNDS; ++t) eb[t * 64 + lane] = stage[t * 64 + lane];
}

// ---- pass 3: fixed-108-round gather + contraction, register accumulation ----
__global__ __launch_bounds__(256, 4) void compute_kernel(
    const uint*  __restrict__ xh,    // [n, 8] dwords (16 bf16)
    const float* __restrict__ Wg,    // [3, 27, 16, 4] f32
    const uint*  __restrict__ ent,   // [NWAVES, EPW]
    float*       __restrict__ out,   // [n, 4]
    int n)
{
    __shared__ __align__(8) uint Wb[NS * K * WREG];   // 81 regions * 34 dwords = 11 KB

    const int tid = threadIdx.x;
    for (int idx = tid; idx < NS * K * 32; idx += 256) {
        const int region = idx >> 5, g = idx & 31;
        Wb[region * WREG + g] =
            bf16_rne(Wg[region * 64 + 2 * g]) | (bf16_rne(Wg[region * 64 + 2 * g + 1]) << 16);
    }
    __syncthreads();

    const int widx = tid >> 6, lane = tid & 63;
    const int w = blockIdx.x * 4 + widx;
    const uint* __restrict__ eb = ent + (size_t)w * EPW;

    f32x4 A0 = {0,0,0,0}, A1 = {0,0,0,0}, A2 = {0,0,0,0}, A3 = {0,0,0,0};

    // pipeline prologue: entries for slots 0,1; x for slot 0
    uint eC = eb[lane];
    uint eN = eb[64 + lane];
    {
        const uint nbC = (eC == SENT) ? 0u : (eC >> 9);
        const u32x4* __restrict__ xr =
            reinterpret_cast<const u32x4*>(xh + (size_t)nbC * 8);
        // fallthrough into loop with xC preloaded
        u32x4 xC0 = xr[0];
        u32x4 xC1 = xr[1];

        for (int s = 0; s < RNDS; ++s) {
            // (1) entry prefetch for slot s+2
            const int sF = (s + 2 < RNDS) ? s + 2 : RNDS - 1;
            const uint eF = eb[sF * 64 + lane];
            // (2) x prefetch for slot s+1
            const uint nbN = (eN == SENT) ? 0u : (eN >> 9);
            const u32x4* __restrict__ xrN =
                reinterpret_cast<const u32x4*>(xh + (size_t)nbN * 8);
            const u32x4 xN0 = xrN[0];
            const u32x4 xN1 = xrN[1];

            // (3) compute slot s
            const bool valid = (eC != SENT);
            const uint bq = valid ? ((eC >> 7) & 3u) : 4u;
            const uint sk = valid ? (((eC >> 5) & 3u) * (uint)K + (eC & 31u)) : 0u;
            const uint* __restrict__ wr = &Wb[sk * WREG];

            uint xd[8];
            xd[0] = xC0.x; xd[1] = xC0.y; xd[2] = xC0.z; xd[3] = xC0.w;
            xd[4] = xC1.x; xd[5] = xC1.y; xd[6] = xC1.z; xd[7] = xC1.w;

            float a0 = 0.f, a1 = 0.f, a2 = 0.f, a3 = 0.f;
            #pragma unroll
            for (int cc = 0; cc < CIN; ++cc) {
                const u32x2 wv = *reinterpret_cast<const u32x2*>(wr + cc * 2); // ds_read_b64
                const float xc = (cc & 1) ? bhi(xd[cc >> 1]) : blo(xd[cc >> 1]);
                a0 = fmaf(xc, blo(wv.x), a0);
                a1 = fmaf(xc, bhi(wv.x), a1);
                a2 = fmaf(xc, blo(wv.y), a2);
                a3 = fmaf(xc, bhi(wv.y), a3);
            }
            const float m0 = (bq == 0u) ? 1.f : 0.f;
            const float m1 = (bq == 1u) ? 1.f : 0.f;
            const float m2 = (bq == 2u) ? 1.f : 0.f;
            const float m3 = (bq == 3u) ? 1.f : 0.f;
            A0.x = fmaf(m0, a0, A0.x); A0.y = fmaf(m0, a1, A0.y);
            A0.z = fmaf(m0, a2, A0.z); A0.w = fmaf(m0, a3, A0.w);
            A1.x = fmaf(m1, a0, A1.x); A1.y = fmaf(m1, a1, A1.y);
            A1.z = fmaf(m1, a2, A1.z); A1.w = fmaf(m1, a3, A1.w);
            A2.x = fmaf(m2, a0, A2.x); A2.y = fmaf(m2, a1, A2.y);
            A2.z = fmaf(m2, a2, A2.z); A2.w = fmaf(m2, a3, A2.w);
            A3.x = fmaf(m3, a0, A3.x); A3.y = fmaf(m3, a1, A3.y);
            A3.z = fmaf(m3, a2, A3.z); A3.w = fmaf(m3, a3, A3.w);

            // rotate pipeline
            eC = eN; xC0 = xN0; xC1 = xN1; eN = eF;
        }
    }

    // epilogue: relu + per-lane 64B contiguous stores
    const int i0 = w * NPW + lane * NPL;
    f32x4* __restrict__ op = reinterpret_cast<f32x4*>(out);
    f32x4 o;
    if (i0 + 0 < n) {
        o.x = fmaxf(A0.x,0.f); o.y = fmaxf(A0.y,0.f); o.z = fmaxf(A0.z,0.f); o.w = fmaxf(A0.w,0.f);
        __builtin_nontemporal_store(o, op + i0 + 0);
    }
    if (i0 + 1 < n) {
        o.x = fmaxf(A1.x,0.f); o.y = fmaxf(A1.y,0.f); o.z = fmaxf(A1.z,0.f); o.w = fmaxf(A1.w,0.f);
        __builtin_nontemporal_store(o, op + i0 + 1);
    }
    if (i0 + 2 < n) {
        o.x = fmaxf(A2.x,0.f); o.y = fmaxf(A2.y,0.f); o.z = fmaxf(A2.z,0.f); o.w = fmaxf(A2.w,0.f);
        __builtin_nontemporal_store(o, op + i0 + 2);
    }
    if (i0 + 3 < n) {
        o.x = fmaxf(A3.x,0.f); o.y = fmaxf(A3.y,0.f); o.z = fmaxf(A3.z,0.f); o.w = fmaxf(A3.w,0.f);
        __builtin_nontemporal_store(o, op + i0 + 3);
    }
}

// ---- fallback: round-4 flat gather kernel (proven ~474 us) ----
__global__ __launch_bounds__(256) void outblock_bf16(
    const uint*  __restrict__ xh,
    const float* __restrict__ W,
    const int*   __restrict__ aprs,
    const int*   __restrict__ lvl,
    float*       __restrict__ out,
    int n)
{
    __shared__ float Wl[NS * WPAD];
    for (int i = threadIdx.x; i < NS * WSZ; i += 256) {
        int s = i / WSZ;
        Wl[s * WPAD + (i - s * WSZ)] = W[i];
    }
    __syncthreads();

    int nIdx = blockIdx.x * 256 + threadIdx.x;
    if (nIdx >= n) return;

    const int s = lvl[nIdx];
    const float* __restrict__ Ws = &Wl[s * WPAD];
    const int*   __restrict__ ap = aprs + (size_t)nIdx * K;

    float a0 = 0.f, a1 = 0.f, a2 = 0.f, a3 = 0.f;
    #pragma unroll 3
    for (int k = 0; k < K; ++k) {
        const int nb = ap[k];
        const u32x4* __restrict__ xr =
            reinterpret_cast<const u32x4*>(xh + (size_t)nb * 8);
        const u32x4 p0 = xr[0];
        const u32x4 p1 = xr[1];
        const float* __restrict__ Wk = Ws + k * (CIN * COUT);
        float xv[16];
        xv[ 0] = blo(p0.x); xv[ 1] = bhi(p0.x);
        xv[ 2] = blo(p0.y); xv[ 3] = bhi(p0.y);
        xv[ 4] = blo(p0.z); xv[ 5] = bhi(p0.z);
        xv[ 6] = blo(p0.w); xv[ 7] = bhi(p0.w);
        xv[ 8] = blo(p1.x); xv[ 9] = bhi(p1.x);
        xv[10] = blo(p1.y); xv[11] = bhi(p1.y);
        xv[12] = blo(p1.z); xv[13] = bhi(p1.z);
        xv[14] = blo(p1.w); xv[15] = bhi(p1.w);
        #pragma unroll
        for (int cq = 0; cq < CIN; ++cq) {
            const float4 wv = *reinterpret_cast<const float4*>(&Wk[cq * COUT]);
            a0 = fmaf(xv[cq], wv.x, a0);
            a1 = fmaf(xv[cq], wv.y, a1);
            a2 = fmaf(xv[cq], wv.z, a2);
            a3 = fmaf(xv[cq], wv.w, a3);
        }
    }
    f32x4 o;
    o.x = fmaxf(a0, 0.f); o.y = fmaxf(a1, 0.f);
    o.z = fmaxf(a2, 0.f); o.w = fmaxf(a3, 0.f);
    __builtin_nontemporal_store(o, reinterpret_cast<f32x4*>(out) + nIdx);
}

// ---- last-resort fp32 fallback ----
__global__ __launch_bounds__(256) void outblock_f32(
    const float* __restrict__ x,
    const float* __restrict__ W,
    const int*   __restrict__ aprs,
    const int*   __restrict__ lvl,
    float*       __restrict__ out,
    int n)
{
    __shared__ float Wl[NS * WPAD];
    for (int i = threadIdx.x; i < NS * WSZ; i += 256) {
        int s = i / WSZ;
        Wl[s * WPAD + (i - s * WSZ)] = W[i];
    }
    __syncthreads();
    int nIdx = blockIdx.x * 256 + threadIdx.x;
    if (nIdx >= n) return;
    const int s = lvl[nIdx];
    const float* __restrict__ Ws = &Wl[s * WPAD];
    const int*   __restrict__ ap = aprs + (size_t)nIdx * K;
    float a0 = 0.f, a1 = 0.f, a2 = 0.f, a3 = 0.f;
    #pragma unroll 3
    for (int k = 0; k < K; ++k) {
        const int nb = ap[k];
        const float4* __restrict__ xr =
            reinterpret_cast<const float4*>(x + (size_t)nb * CIN);
        const float4 v0 = xr[0], v1 = xr[1], v2 = xr[2], v3 = xr[3];
        const float* __restrict__ Wk = Ws + k * (CIN * COUT);
        float xv[16];
        xv[ 0] = v0.x; xv[ 1] = v0.y; xv[ 2] = v0.z; xv[ 3] = v0.w;
        xv[ 4] = v1.x; xv[ 5] = v1.y; xv[ 6] = v1.z; xv[ 7] = v1.w;
        xv[ 8] = v2.x; xv[ 9] = v2.y; xv[10] = v2.z; xv[11] = v2.w;
        xv[12] = v3.x; xv[13] = v3.y; xv[14] = v3.z; xv[15] = v3.w;
        #pragma unroll
        for (int cq = 0; cq < CIN; ++cq) {
            const float4 wv = *reinterpret_cast<const float4*>(&Wk[cq * COUT]);
            a0 = fmaf(xv[cq], wv.x, a0);
            a1 = fmaf(xv[cq], wv.y, a1);
            a2 = fmaf(xv[cq], wv.z, a2);
            a3 = fmaf(xv[cq], wv.w, a3);
        }
    }
    float4 o;
    o.x = fmaxf(a0, 0.f); o.y = fmaxf(a1, 0.f);
    o.z = fmaxf(a2, 0.f); o.w = fmaxf(a3, 0.f);
    reinterpret_cast<float4*>(out)[nIdx] = o;
}

extern "C" void kernel_launch(void* const* d_in, const int* in_sizes, int n_in,
                              void* d_out, int out_size, void* d_ws, size_t ws_size,
                              hipStream_t stream) {
    const float* x    = (const float*)d_in[0];
    const float* W    = (const float*)d_in[1];
    const int*   aprs = (const int*)d_in[2];
    const int*   lvl  = (const int*)d_in[3];
    float*       out  = (float*)d_out;

    const int n = in_sizes[0] / CIN;               // N particles

    // waves needed, rounded up to 4 (compute block = 4 waves)
    const int nwaves = ((n + NPW - 1) / NPW + 3) & ~3;
    const int nblocks = nwaves / 4;

    const size_t xhB  = (size_t)n * CIN * 2;             // 32 MB bf16 x copy
    const size_t entB = (size_t)nwaves * EPW * 4;        // ~108 MB entries
    const size_t needChunked = xhB + entB;

    if (ws_size >= needChunked && n <= (1 << 20)) {
        uint* xh  = (uint*)d_ws;
        uint* ent = (uint*)((char*)d_ws + xhB);
        const int nvec = n * CIN / 8;
        cvt_kernel<<<(nvec + 255) / 256, 256, 0, stream>>>(x, xh, nvec);
        bucket_kernel<<<nwaves, 64, 0, stream>>>(aprs, lvl, ent, n);
        compute_kernel<<<nblocks, 256, 0, stream>>>(xh, W, ent, out, n);
    } else if (ws_size >= xhB) {
        uint* xh = (uint*)d_ws;
        const int nvec = n * CIN / 8;
        cvt_kernel<<<(nvec + 255) / 256, 256, 0, stream>>>(x, xh, nvec);
        outblock_bf16<<<(n + 255) / 256, 256, 0, stream>>>(xh, W, aprs, lvl, out, n);
    } else {
        outblock_f32<<<(n + 255) / 256, 256, 0, stream>>>(x, W, aprs, lvl, out, n);
    }
}